// Round 1
// baseline (449.990 us; speedup 1.0000x reference)
//
#include <hip/hip_runtime.h>

#define NB 4
#define CIN 8
#define CO 16
#define NV 100000
#define NM 98304

typedef short s16x8 __attribute__((ext_vector_type(8)));
typedef float f32x4 __attribute__((ext_vector_type(4)));
typedef unsigned short u16;

// ws layout (bytes, all offsets multiple of 128)
#define OFF_ACC  0
#define SZ_ACC   (NB*NV*CO*4)            // 25,600,000
#define OFF_CNT  (SZ_ACC)                 // 25,600,000
#define SZ_CNT   (NV*4)                   // 400,000
#define OFF_STAT (OFF_CNT + SZ_CNT)       // 26,000,000
#define SZ_STAT  256                      // sum[16], sq[16], scale[16], shift[16]
#define OFF_XTB  (OFF_STAT + 384)         // 26,000,384
#define SZ_XTB   (NV*32*2)                // 6,400,000
#define OFF_W1B  (OFF_XTB + SZ_XTB)       // 32,400,384
#define SZ_W1B   (128*64*2)
#define OFF_W2B  (OFF_W1B + SZ_W1B)
#define SZ_W2B   (128*128*2)
#define OFF_H1   (OFF_W2B + SZ_W2B)
#define SZ_H1    (NB*NV*CO*2)             // 12,800,000
#define WS_NEED  (OFF_H1 + SZ_H1)

static __device__ __forceinline__ u16 f2bf(float f){
  union { float f; unsigned int u; } v; v.f = f;
  unsigned int r = v.u + 0x7fffu + ((v.u >> 16) & 1u);
  return (u16)(r >> 16);
}

// ---------- prep: count + transpose x -> xtb[v][b*8+c] bf16 + W->bf16 ----------
__global__ __launch_bounds__(256) void k_prep(const int* __restrict__ elem,
    const float* __restrict__ x, const float* __restrict__ W1, const float* __restrict__ W2,
    float* __restrict__ cnt, u16* __restrict__ xtb, u16* __restrict__ w1b, u16* __restrict__ w2b)
{
  const int T1 = NM*8;
  const int T2 = T1 + NV*32;
  const int T3 = T2 + 128*64;
  const int T4 = T3 + 128*128;
  int stride = gridDim.x*blockDim.x;
  for (int i = blockIdx.x*blockDim.x + threadIdx.x; i < T4; i += stride){
    if (i < T1) { unsafeAtomicAdd(cnt + elem[i], 1.0f); }
    else if (i < T2){ int j = i - T1; xtb[j] = f2bf(x[(size_t)(j & 31)*NV + (j >> 5)]); }
    else if (i < T3){ int j = i - T2; w1b[j] = f2bf(W1[j]); }
    else { int j = i - T3; w2b[j] = f2bf(W2[j]); }
  }
}

// ---------- conv1: gather-GEMM-scatter, K=64 ----------
// GEMM rows r = m*4 + b; wave handles 16 rows (4 elements x 4 batches).
__global__ __launch_bounds__(256) void k_conv1(const int* __restrict__ elem,
    const u16* __restrict__ xtb, const u16* __restrict__ w1b,
    const float* __restrict__ b1, float* __restrict__ acc)
{
  const int lane = threadIdx.x & 63;
  const int col = lane & 15, kg = lane >> 4;
  s16x8 wf[8][2];
  #pragma unroll
  for (int j2 = 0; j2 < 8; j2++)
    #pragma unroll
    for (int t = 0; t < 2; t++)
      wf[j2][t] = *(const s16x8*)(w1b + (j2*16 + col)*64 + t*32 + kg*8);

  int wave = (int)((blockIdx.x*blockDim.x + threadIdx.x) >> 6);
  int nw   = (int)((gridDim.x*blockDim.x) >> 6);
  const int ngrp = (NM*NB) >> 4;   // 24576
  for (int g = wave; g < ngrp; g += nw){
    int m_a = g*4 + ((lane & 15) >> 2);   // element for this lane's A-row
    int b   = lane & 3;
    s16x8 af0 = *(const s16x8*)(xtb + (size_t)elem[m_a*8 + kg    ]*32 + b*8);
    s16x8 af1 = *(const s16x8*)(xtb + (size_t)elem[m_a*8 + 4 + kg]*32 + b*8);
    int m_e = g*4 + kg;                   // element for this lane's D-rows (batches q=0..3)
    #pragma unroll
    for (int j2 = 0; j2 < 8; j2++){
      f32x4 c = {0.f, 0.f, 0.f, 0.f};
      c = __builtin_amdgcn_mfma_f32_16x16x32_bf16(af0, wf[j2][0], c, 0, 0, 0);
      c = __builtin_amdgcn_mfma_f32_16x16x32_bf16(af1, wf[j2][1], c, 0, 0, 0);
      int vout = elem[m_e*8 + j2];
      float bb = b1[j2*16 + col];
      float* dst = acc + (size_t)vout*16 + col;
      #pragma unroll
      for (int q = 0; q < 4; q++)
        unsafeAtomicAdd(dst + (size_t)q*NV*16, c[q] + bb);
    }
  }
}

// ---------- conv2: K=128, input h1[B][N][16] bf16 ----------
__global__ __launch_bounds__(256) void k_conv2(const int* __restrict__ elem,
    const u16* __restrict__ h1, const u16* __restrict__ w2b,
    const float* __restrict__ b2, float* __restrict__ acc)
{
  const int lane = threadIdx.x & 63;
  const int col = lane & 15, kg = lane >> 4;
  s16x8 wf[8][4];
  #pragma unroll
  for (int j2 = 0; j2 < 8; j2++)
    #pragma unroll
    for (int t = 0; t < 4; t++)
      wf[j2][t] = *(const s16x8*)(w2b + (j2*16 + col)*128 + t*32 + kg*8);

  int wave = (int)((blockIdx.x*blockDim.x + threadIdx.x) >> 6);
  int nw   = (int)((gridDim.x*blockDim.x) >> 6);
  const int ngrp = (NM*NB) >> 4;
  for (int g = wave; g < ngrp; g += nw){
    int m_a = g*4 + ((lane & 15) >> 2);
    int b   = lane & 3;
    s16x8 af[4];
    #pragma unroll
    for (int t = 0; t < 4; t++){
      int k0 = t*32 + kg*8;
      int j  = k0 >> 4;
      int c0 = k0 & 15;
      int v  = elem[m_a*8 + j];
      af[t] = *(const s16x8*)(h1 + ((size_t)b*NV + v)*16 + c0);
    }
    int m_e = g*4 + kg;
    #pragma unroll
    for (int j2 = 0; j2 < 8; j2++){
      f32x4 c = {0.f, 0.f, 0.f, 0.f};
      #pragma unroll
      for (int t = 0; t < 4; t++)
        c = __builtin_amdgcn_mfma_f32_16x16x32_bf16(af[t], wf[j2][t], c, 0, 0, 0);
      int vout = elem[m_e*8 + j2];
      float bb = b2[j2*16 + col];
      float* dst = acc + (size_t)vout*16 + col;
      #pragma unroll
      for (int q = 0; q < 4; q++)
        unsafeAtomicAdd(dst + (size_t)q*NV*16, c[q] + bb);
    }
  }
}

// ---------- BN stats: sum/sumsq per channel of acc/cnt ----------
__global__ __launch_bounds__(256) void k_stats(const float* __restrict__ acc,
    const float* __restrict__ cnt, float* __restrict__ stat)
{
  int b = blockIdx.y;
  float s[16], q[16];
  #pragma unroll
  for (int i = 0; i < 16; i++){ s[i] = 0.f; q[i] = 0.f; }
  for (int n = blockIdx.x*blockDim.x + threadIdx.x; n < NV; n += gridDim.x*blockDim.x){
    float inv = 1.0f / fmaxf(cnt[n], 1.0f);
    const f32x4* a4 = (const f32x4*)(acc + ((size_t)b*NV + n)*16);
    #pragma unroll
    for (int k = 0; k < 4; k++){
      f32x4 v = a4[k];
      #pragma unroll
      for (int t = 0; t < 4; t++){
        float xv = v[t]*inv;
        s[k*4+t] += xv; q[k*4+t] += xv*xv;
      }
    }
  }
  #pragma unroll
  for (int i = 0; i < 16; i++){
    #pragma unroll
    for (int off = 32; off > 0; off >>= 1){
      s[i] += __shfl_down(s[i], off);
      q[i] += __shfl_down(q[i], off);
    }
  }
  __shared__ float ls[4][32];
  int wid = threadIdx.x >> 6, lane = threadIdx.x & 63;
  if (lane == 0){
    #pragma unroll
    for (int i = 0; i < 16; i++){ ls[wid][i] = s[i]; ls[wid][16+i] = q[i]; }
  }
  __syncthreads();
  if (threadIdx.x < 32){
    float v = ls[0][threadIdx.x] + ls[1][threadIdx.x] + ls[2][threadIdx.x] + ls[3][threadIdx.x];
    unsafeAtomicAdd(stat + threadIdx.x, v);
  }
}

__global__ void k_finalize(float* __restrict__ stat, const float* __restrict__ gamma,
                           const float* __restrict__ beta)
{
  int co = threadIdx.x;
  if (co < 16){
    const float invn = 1.0f / (float)(NB*NV);
    float meanv = stat[co]*invn;
    float var   = stat[16+co]*invn - meanv*meanv;
    float sc = gamma[co]*rsqrtf(var + 1e-5f);
    stat[32+co] = sc;
    stat[48+co] = beta[co] - meanv*sc;
  }
}

// ---------- apply BN1 + relu -> h1 bf16 ----------
__global__ __launch_bounds__(256) void k_apply1(const float* __restrict__ acc,
    const float* __restrict__ cnt, const float* __restrict__ stat, u16* __restrict__ h1)
{
  int n = blockIdx.x*blockDim.x + threadIdx.x;
  int b = blockIdx.y;
  if (n >= NV) return;
  float inv = 1.0f / fmaxf(cnt[n], 1.0f);
  const f32x4* a4 = (const f32x4*)(acc + ((size_t)b*NV + n)*16);
  u16 o[16] __attribute__((aligned(16)));
  #pragma unroll
  for (int k = 0; k < 4; k++){
    f32x4 v = a4[k];
    #pragma unroll
    for (int t = 0; t < 4; t++){
      int co = k*4 + t;
      float val = v[t]*inv*stat[32+co] + stat[48+co];
      o[co] = f2bf(fmaxf(val, 0.f));
    }
  }
  uint4* dst = (uint4*)(h1 + ((size_t)b*NV + n)*16);
  dst[0] = *(uint4*)(o);
  dst[1] = *(uint4*)(o + 8);
}

// ---------- final: BN2 + skip GEMV + relu + transpose to [B][Co][N] ----------
__global__ __launch_bounds__(256) void k_final(const float* __restrict__ acc,
    const float* __restrict__ cnt, const float* __restrict__ stat,
    const float* __restrict__ x, const float* __restrict__ wsk,
    const float* __restrict__ bsk, float* __restrict__ out)
{
  int n = blockIdx.x*blockDim.x + threadIdx.x;
  int b = blockIdx.y;
  if (n >= NV) return;
  float inv = 1.0f / fmaxf(cnt[n], 1.0f);
  float xv[8];
  #pragma unroll
  for (int c = 0; c < 8; c++) xv[c] = x[((size_t)b*8 + c)*NV + n];
  const f32x4* a4 = (const f32x4*)(acc + ((size_t)b*NV + n)*16);
  #pragma unroll
  for (int k = 0; k < 4; k++){
    f32x4 v = a4[k];
    #pragma unroll
    for (int t = 0; t < 4; t++){
      int co = k*4 + t;
      float val = v[t]*inv*stat[32+co] + stat[48+co] + bsk[co];
      #pragma unroll
      for (int c = 0; c < 8; c++) val += wsk[co*8+c]*xv[c];
      out[((size_t)b*16 + co)*NV + n] = fmaxf(val, 0.f);
    }
  }
}

extern "C" void kernel_launch(void* const* d_in, const int* in_sizes, int n_in,
                              void* d_out, int out_size, void* d_ws, size_t ws_size,
                              hipStream_t stream) {
  const float* x    = (const float*)d_in[0];
  const int*   elem = (const int*)  d_in[1];
  const float* W1   = (const float*)d_in[2];
  const float* b1   = (const float*)d_in[3];
  const float* g1   = (const float*)d_in[4];
  const float* be1  = (const float*)d_in[5];
  const float* W2   = (const float*)d_in[6];
  const float* b2   = (const float*)d_in[7];
  const float* g2   = (const float*)d_in[8];
  const float* be2  = (const float*)d_in[9];
  const float* Wsk  = (const float*)d_in[10];
  const float* bsk  = (const float*)d_in[11];
  float* out = (float*)d_out;

  if (ws_size < (size_t)WS_NEED) return;  // visible failure rather than corruption

  char* ws = (char*)d_ws;
  float* acc  = (float*)(ws + OFF_ACC);
  float* cnt  = (float*)(ws + OFF_CNT);
  float* stat = (float*)(ws + OFF_STAT);
  u16*   xtb  = (u16*)  (ws + OFF_XTB);
  u16*   w1b  = (u16*)  (ws + OFF_W1B);
  u16*   w2b  = (u16*)  (ws + OFF_W2B);
  u16*   h1   = (u16*)  (ws + OFF_H1);

  // zero acc + cnt + stat (contiguous)
  hipMemsetAsync(ws, 0, OFF_STAT + SZ_STAT, stream);

  k_prep<<<4096, 256, 0, stream>>>(elem, x, W1, W2, cnt, xtb, w1b, w2b);
  k_conv1<<<3072, 256, 0, stream>>>(elem, xtb, w1b, b1, acc);
  k_stats<<<dim3(128, NB), 256, 0, stream>>>(acc, cnt, stat);
  k_finalize<<<1, 64, 0, stream>>>(stat, g1, be1);
  k_apply1<<<dim3((NV+255)/256, NB), 256, 0, stream>>>(acc, cnt, stat, h1);

  hipMemsetAsync(ws + OFF_ACC, 0, SZ_ACC, stream);
  hipMemsetAsync(ws + OFF_STAT, 0, SZ_STAT, stream);

  k_conv2<<<3072, 256, 0, stream>>>(elem, h1, w2b, b2, acc);
  k_stats<<<dim3(128, NB), 256, 0, stream>>>(acc, cnt, stat);
  k_finalize<<<1, 64, 0, stream>>>(stat, g2, be2);
  k_final<<<dim3((NV+255)/256, NB), 256, 0, stream>>>(acc, cnt, stat, x, Wsk, bsk, out);
}